// Round 1
// baseline (84.905 us; speedup 1.0000x reference)
//
#include <hip/hip_runtime.h>
#include <math.h>

#define J   29
#define CH  3
#define JC  87            // J*CH
#define E0  56
#define B   256
#define T   1024
#define FRAMES (B*T)      // 262144
#define FPB 128           // frames per block (== threads per block)
#define NBLK (FRAMES/FPB) // 2048
#define BPB (T/FPB)       // main-kernel blocks per batch = 8

// ---------------- prep: build CSR of M = D^-1/2 (A+I) D^-1/2 ----------------
__global__ void prep_kernel(const int* __restrict__ ei,
                            int* __restrict__ rowptr,
                            int* __restrict__ cols,
                            float* __restrict__ vals) {
    __shared__ float M[J * J];
    __shared__ float dinv[J];
    __shared__ int   cnt[J];
    int tid = threadIdx.x;

    for (int i = tid; i < J * J; i += 64) M[i] = 0.f;
    if (tid < J) {
        int d = 1;  // self loop
        for (int e = 0; e < E0; ++e) d += (ei[E0 + e] == tid) ? 1 : 0;
        dinv[tid] = rsqrtf((float)d);
    }
    __syncthreads();

    if (tid < J) {
        // row j = tid: edges with dst == j (duplicates accumulate)
        for (int e = 0; e < E0; ++e) {
            if (ei[E0 + e] == tid) {
                int s = ei[e];
                M[tid * J + s] += dinv[s] * dinv[tid];
            }
        }
        M[tid * J + tid] += dinv[tid] * dinv[tid];
        int c = 0;
        for (int i = 0; i < J; ++i) c += (M[tid * J + i] != 0.f) ? 1 : 0;
        cnt[tid] = c;
    }
    __syncthreads();

    if (tid == 0) {
        int acc = 0;
        for (int j = 0; j < J; ++j) { rowptr[j] = acc; acc += cnt[j]; }
        rowptr[J] = acc;
    }
    __syncthreads();

    if (tid < J) {
        int p = rowptr[tid];
        for (int i = 0; i < J; ++i) {
            float v = M[tid * J + i];
            if (v != 0.f) { cols[p] = i; vals[p] = v; ++p; }
        }
    }
}

// ---------------- main: per-frame GCN + ReLU, block-level frame-sum ----------
__launch_bounds__(FPB)
__global__ void gcn_main(const float* __restrict__ x,
                         const float* __restrict__ Wp,
                         const float* __restrict__ bp,
                         const int* __restrict__ rowptr,
                         const int* __restrict__ cols,
                         const float* __restrict__ vals,
                         float* __restrict__ partials) {
    __shared__ float xs[FPB * JC];   // 44544 B; reused for reduction
    __shared__ int   s_rp[J + 1];
    __shared__ int   s_cols[85];
    __shared__ float s_vals[85];
    __shared__ float s_W[9];
    __shared__ float s_b[3];

    int tid = threadIdx.x;

    if (tid < 9)      s_W[tid] = Wp[tid];
    if (tid < 3)      s_b[tid] = bp[tid];
    if (tid <= J)     s_rp[tid] = rowptr[tid];
    if (tid < 85) { s_cols[tid] = cols[tid]; s_vals[tid] = vals[tid]; }

    // coalesced stage of 128 frames (11136 floats = 2784 float4)
    {
        const float4* src4 = (const float4*)(x + (size_t)blockIdx.x * (FPB * JC));
        float4* dst4 = (float4*)xs;
        for (int i = tid; i < (FPB * JC) / 4; i += FPB) dst4[i] = src4[i];
    }
    __syncthreads();

    // y = M @ x_frame  (sparse CSR, static row indexing)
    float y[J][CH];
    const float* xf = xs + tid * JC;
#pragma unroll
    for (int j = 0; j < J; ++j) {
        float a0 = 0.f, a1 = 0.f, a2 = 0.f;
        int e0 = s_rp[j], e1 = s_rp[j + 1];
        for (int e = e0; e < e1; ++e) {
            int   sc = s_cols[e] * CH;
            float nv = s_vals[e];
            a0 += nv * xf[sc + 0];
            a1 += nv * xf[sc + 1];
            a2 += nv * xf[sc + 2];
        }
        y[j][0] = a0; y[j][1] = a1; y[j][2] = a2;
    }

    // agg = y @ W + b, ReLU, store back into own LDS region (thread-private)
#pragma unroll
    for (int j = 0; j < J; ++j) {
#pragma unroll
        for (int c = 0; c < CH; ++c) {
            float a = y[j][0] * s_W[0 * CH + c]
                    + y[j][1] * s_W[1 * CH + c]
                    + y[j][2] * s_W[2 * CH + c]
                    + s_b[c];
            xs[tid * JC + j * CH + c] = fmaxf(a, 0.f);
        }
    }
    __syncthreads();

    // tree-reduce 128 frame-vectors -> 1 (87 components)
#pragma unroll
    for (int ls = 6; ls >= 0; --ls) {
        int s = 1 << ls;
        for (int w = tid; w < s * JC; w += FPB) {
            int t = w & (s - 1);
            int r = w >> ls;
            xs[t * JC + r] += xs[(t + s) * JC + r];
        }
        __syncthreads();
    }

    if (tid < JC) partials[(size_t)blockIdx.x * JC + tid] = xs[tid];
}

// ---------------- finalize: mean over frames + fc + sigmoid ------------------
__global__ void finalize_kernel(const float* __restrict__ partials,
                                const float* __restrict__ fcW,
                                const float* __restrict__ fcb,
                                float* __restrict__ out) {
    __shared__ float h[JC];
    int b = blockIdx.x, tid = threadIdx.x;
    if (tid < JC) {
        float a = 0.f;
#pragma unroll
        for (int p = 0; p < BPB; ++p)
            a += partials[(size_t)(b * BPB + p) * JC + tid];
        a *= (1.0f / (float)T);
        h[tid] = a;
        out[(size_t)b * JC + tid] = a;
    }
    __syncthreads();
    if (tid < 2) {
        float a = fcb[tid];
        for (int r = 0; r < JC; ++r) a += h[r] * fcW[r * 2 + tid];
        out[(size_t)B * JC + b * 2 + tid] = 1.0f / (1.0f + expf(-a));
    }
}

extern "C" void kernel_launch(void* const* d_in, const int* in_sizes, int n_in,
                              void* d_out, int out_size, void* d_ws, size_t ws_size,
                              hipStream_t stream) {
    const float* x   = (const float*)d_in[0];
    const int*   ei  = (const int*)d_in[1];
    // d_in[2] = batch_size, d_in[3] = num_frames (hardcoded 256/1024)
    const float* W   = (const float*)d_in[4];
    const float* bb  = (const float*)d_in[5];
    const float* fcW = (const float*)d_in[6];
    const float* fcb = (const float*)d_in[7];

    int*   wsI      = (int*)d_ws;
    int*   rowptr   = wsI;                 // [30]
    int*   cols     = wsI + 32;            // [85]
    float* vals     = (float*)(wsI + 128); // [85]
    float* partials = (float*)(wsI + 256); // [2048*87]

    prep_kernel<<<1, 64, 0, stream>>>(ei, rowptr, cols, vals);
    gcn_main<<<NBLK, FPB, 0, stream>>>(x, W, bb, rowptr, cols, vals, partials);
    finalize_kernel<<<B, 128, 0, stream>>>(partials, fcW, fcb, (float*)d_out);
}